// Round 1
// baseline (1725.260 us; speedup 1.0000x reference)
//
#include <hip/hip_runtime.h>
#include <math.h>

#define MUL 32
#define NATTR 4
#define NBASIS 10
#define HID 64
#define OUT_DIM 16
#define NGRAPH 8

#define PI_F 3.14159265358979323846f
#define SQRT3_F 1.7320508075688772f
#define INV_SQRT3_F 0.5773502691896258f
#define INV_SQRT10_F 0.31622776601683794f
#define INV_SQRTNN_F 0.17677669529663687f   // 1/sqrt(32)
#define NORM128_F 0.08838834764831845f      // 1/sqrt(128)
#define NORM256_F 0.0625f                   // 1/sqrt(256)
#define C_S_F 0.3826834323650898f           // sin(pi/8)
#define C_X_F 0.9238795325112867f           // cos(pi/8)
#define CSTEP_F (4.0f/9.0f)                 // linspace(0,4,10) step

// ---------------------------------------------------------------- init s,v
__global__ void init_sv(const float* __restrict__ x,
                        float* __restrict__ s, float* __restrict__ v, int N) {
    int i = blockIdx.x * 256 + threadIdx.x;
    if (i >= N * 128) return;
    int n = i >> 7, c = i & 127;
    float val = x[i];
    if (c < 32) s[n * 32 + c] = val;
    else        v[n * 96 + (c - 32)] = val;
}

// ------------------------------------------- node fctp, scalar path (s -> 2 outputs)
// out0[n,w] = sum_{u,a} s[n,u]*attr[n,a]*W0[u,a,w] / sqrt(128); same for out1/W1
__global__ __launch_bounds__(256, 4) void node_s_fctp(
    const float* __restrict__ s, const float* __restrict__ attr,
    const float* __restrict__ W0, const float* __restrict__ W1,
    float* __restrict__ out0, float* __restrict__ out1, int N) {
    __shared__ float w0[4096], w1[4096];
    __shared__ float sh_s[8][32];
    int ln = threadIdx.x >> 5, w = threadIdx.x & 31;
    int n = blockIdx.x * 8 + ln;
    bool valid = n < N;
    if (valid) sh_s[ln][w] = s[n * 32 + w];
    for (int i = threadIdx.x; i < 4096; i += 256) { w0[i] = W0[i]; w1[i] = W1[i]; }
    __syncthreads();
    if (!valid) return;
    float4 at = *(const float4*)(attr + n * 4);
    float fa[4] = {at.x, at.y, at.z, at.w};
    float acc0 = 0.f, acc1 = 0.f;
    for (int u = 0; u < 32; u++) {
        float su = sh_s[ln][u];
        int base = u * 128 + w;
#pragma unroll
        for (int a = 0; a < 4; a++) {
            float c = su * fa[a];
            acc0 += c * w0[base + a * 32];
            acc1 += c * w1[base + a * 32];
        }
    }
    out0[n * 32 + w] = acc0 * NORM128_F;
    out1[n * 32 + w] = acc1 * NORM128_F;
}

// ------------------------------------------- node fctp, vector path (v -> 2 outputs)
__global__ __launch_bounds__(256, 4) void node_v_fctp(
    const float* __restrict__ v, const float* __restrict__ attr,
    const float* __restrict__ W0, const float* __restrict__ W1,
    float* __restrict__ out0, float* __restrict__ out1, int N) {
    __shared__ float w0[4096], w1[4096];
    __shared__ float sh_v[8][96];
    int ln = threadIdx.x >> 5, w = threadIdx.x & 31;
    int n = blockIdx.x * 8 + ln;
    bool valid = n < N;
    if (valid) {
        sh_v[ln][w * 3 + 0] = v[n * 96 + w * 3 + 0];
        sh_v[ln][w * 3 + 1] = v[n * 96 + w * 3 + 1];
        sh_v[ln][w * 3 + 2] = v[n * 96 + w * 3 + 2];
    }
    for (int i = threadIdx.x; i < 4096; i += 256) { w0[i] = W0[i]; w1[i] = W1[i]; }
    __syncthreads();
    if (!valid) return;
    float4 at = *(const float4*)(attr + n * 4);
    float fa[4] = {at.x, at.y, at.z, at.w};
    float a00 = 0, a01 = 0, a02 = 0, a10 = 0, a11 = 0, a12 = 0;
    for (int u = 0; u < 32; u++) {
        float vu0 = sh_v[ln][u * 3 + 0];
        float vu1 = sh_v[ln][u * 3 + 1];
        float vu2 = sh_v[ln][u * 3 + 2];
        int base = u * 128 + w;
#pragma unroll
        for (int a = 0; a < 4; a++) {
            float f = fa[a];
            float c0 = vu0 * f, c1 = vu1 * f, c2 = vu2 * f;
            float W0v = w0[base + a * 32], W1v = w1[base + a * 32];
            a00 += c0 * W0v; a01 += c1 * W0v; a02 += c2 * W0v;
            a10 += c0 * W1v; a11 += c1 * W1v; a12 += c2 * W1v;
        }
    }
    out0[n * 96 + w * 3 + 0] = a00 * NORM128_F;
    out0[n * 96 + w * 3 + 1] = a01 * NORM128_F;
    out0[n * 96 + w * 3 + 2] = a02 * NORM128_F;
    out1[n * 96 + w * 3 + 0] = a10 * NORM128_F;
    out1[n * 96 + w * 3 + 1] = a11 * NORM128_F;
    out1[n * 96 + w * 3 + 2] = a12 * NORM128_F;
}

// ---------------------------------------------------------------- edge kernel
// 64 edges per block. Phases: geom+emb -> h GEMM -> w GEMM (register-tiled)
// -> gather/compute/scatter with atomics.
__global__ __launch_bounds__(256, 2) void edge_msg(
    const float* __restrict__ edge_vec,
    const int* __restrict__ esrc, const int* __restrict__ edst,
    const float* __restrict__ xs, const float* __restrict__ xv,
    const float* __restrict__ Wfc1, const float* __restrict__ Wfc2,
    float* __restrict__ agg_s, float* __restrict__ agg_v, int E) {
    __shared__ float sh_wfc1[NBASIS * 64];   // [j][k]
    __shared__ float sh_embT[NBASIS * 64];   // [j][e]
    __shared__ float sh_h[64 * 65];          // [e][k], stride 65 kills bank conflicts
    __shared__ float sh_w[64 * 128];         // [e][w]
    __shared__ float sh_y[64 * 3];
    __shared__ int sh_src[64], sh_dst[64];

    int tid = threadIdx.x;
    int e0 = blockIdx.x * 64;

    for (int i = tid; i < 640; i += 256) sh_wfc1[i] = Wfc1[i];
    if (tid < 64) {
        int e = e0 + tid;
        float ex = 0.f, ey = 0.f, ez = 0.f;
        if (e < E) {
            ex = edge_vec[e * 3 + 0]; ey = edge_vec[e * 3 + 1]; ez = edge_vec[e * 3 + 2];
            sh_src[tid] = esrc[e]; sh_dst[tid] = edst[e];
        } else { sh_src[tid] = 0; sh_dst[tid] = 0; }
        float len = sqrtf(ex * ex + ey * ey + ez * ez);
        float rinv = SQRT3_F / (len + 1e-9f);
        sh_y[tid * 3 + 0] = ex * rinv;
        sh_y[tid * 3 + 1] = ey * rinv;
        sh_y[tid * 3 + 2] = ez * rinv;
        float uu = 2.0f * (len * 0.25f - 1.0f);
        float cut = (uu > 0.0f) ? 0.0f
                  : ((uu < -1.0f) ? 1.0f : 0.5f * (1.0f - __cosf(PI_F * uu)));
#pragma unroll
        for (int j = 0; j < NBASIS; j++) {
            float d = (len - j * CSTEP_F) * 2.5f;
            sh_embT[j * 64 + tid] = __expf(-d * d) * cut;
        }
    }
    __syncthreads();

    // ---- phase 1: h[e][k] = silu((emb @ Wfc1)/sqrt(10))
    {
        int k = tid & 63;
        int eb = (tid >> 6) * 16;
        float acc[16];
#pragma unroll
        for (int i = 0; i < 16; i++) acc[i] = 0.f;
#pragma unroll
        for (int j = 0; j < NBASIS; j++) {
            float wv = sh_wfc1[j * 64 + k];
#pragma unroll
            for (int i = 0; i < 16; i++) acc[i] += wv * sh_embT[j * 64 + eb + i];
        }
#pragma unroll
        for (int i = 0; i < 16; i++) {
            float a = acc[i] * INV_SQRT10_F;
            sh_h[(eb + i) * 65 + k] = a / (1.0f + __expf(-a));
        }
    }
    __syncthreads();

    // ---- phase 2: w[e][c] = (h @ Wfc2)/8 ; register tile 4 edges x 8 outputs
    {
        int wt = tid & 15;   // outputs wt*8 .. wt*8+7
        int et = tid >> 4;   // edges  et*4 .. et*4+3
        float acc[4][8];
#pragma unroll
        for (int ie = 0; ie < 4; ie++)
#pragma unroll
            for (int j = 0; j < 8; j++) acc[ie][j] = 0.f;
        const float* W2 = Wfc2 + wt * 8;
#pragma unroll 4
        for (int k = 0; k < HID; k++) {
            float4 b0 = *(const float4*)(W2 + k * 128);
            float4 b1 = *(const float4*)(W2 + k * 128 + 4);
            float bv[8] = {b0.x, b0.y, b0.z, b0.w, b1.x, b1.y, b1.z, b1.w};
            float hv[4];
#pragma unroll
            for (int ie = 0; ie < 4; ie++) hv[ie] = sh_h[(et * 4 + ie) * 65 + k];
#pragma unroll
            for (int ie = 0; ie < 4; ie++)
#pragma unroll
                for (int j = 0; j < 8; j++) acc[ie][j] += hv[ie] * bv[j];
        }
#pragma unroll
        for (int ie = 0; ie < 4; ie++) {
            float* dst = sh_w + (et * 4 + ie) * 128 + wt * 8;
#pragma unroll
            for (int j = 0; j < 8; j++) dst[j] = acc[ie][j] * 0.125f;
        }
    }
    __syncthreads();

    // ---- phase 3: per-edge gather + message + atomic scatter (wave per edge)
    {
        int lane = tid & 63;
        int wv = tid >> 6;
#pragma unroll 2
        for (int pass = 0; pass < 16; pass++) {
            int le = pass * 4 + wv;
            int e = e0 + le;
            if (e >= E) continue;
            int sIdx = sh_src[le], d = sh_dst[le];
            float y0 = sh_y[le * 3 + 0], y1 = sh_y[le * 3 + 1], y2 = sh_y[le * 3 + 2];
            float ms, mv0, mv1, mv2;
            if (lane < 32) {
                float sE = xs[sIdx * 32 + lane];
                float wa = sh_w[le * 128 + lane];        // c=0
                float wc = sh_w[le * 128 + 64 + lane];   // c=2
                ms = wa * sE;
                float t = wc * sE;
                mv0 = t * y0; mv1 = t * y1; mv2 = t * y2;
            } else {
                int uu = lane - 32;
                const float* vp = xv + sIdx * 96 + uu * 3;
                float vE0 = vp[0], vE1 = vp[1], vE2 = vp[2];
                float wb = sh_w[le * 128 + 32 + uu];     // c=1
                float wd = sh_w[le * 128 + 96 + uu];     // c=3
                ms = wb * (y0 * vE0 + y1 * vE1 + y2 * vE2) * INV_SQRT3_F;
                mv0 = wd * vE0; mv1 = wd * vE1; mv2 = wd * vE2;
            }
            atomicAdd(&agg_s[d * 64 + lane], ms * INV_SQRTNN_F);
            float* av = agg_v + (size_t)d * 192 + lane * 3;
            atomicAdd(av + 0, mv0 * INV_SQRTNN_F);
            atomicAdd(av + 1, mv1 * INV_SQRTNN_F);
            atomicAdd(av + 2, mv2 * INV_SQRTNN_F);
        }
    }
}

// ------------------------------------------- second fctp (64-wide) + s update
__global__ __launch_bounds__(256, 4) void node_update_s(
    const float* __restrict__ agg_s, const float* __restrict__ attr,
    const float* __restrict__ W0, const float* __restrict__ sc_s,
    float* __restrict__ s, float* __restrict__ snew, int N) {
    __shared__ float w0[8192];
    __shared__ float sh_as[8][64];
    int ln = threadIdx.x >> 5, w = threadIdx.x & 31;
    int n = blockIdx.x * 8 + ln;
    bool valid = n < N;
    if (valid) {
        sh_as[ln][w] = agg_s[n * 64 + w];
        sh_as[ln][32 + w] = agg_s[n * 64 + 32 + w];
    }
    for (int i = threadIdx.x; i < 8192; i += 256) w0[i] = W0[i];
    __syncthreads();
    if (!valid) return;
    float4 at = *(const float4*)(attr + n * 4);
    float fa[4] = {at.x, at.y, at.z, at.w};
    float acc = 0.f;
    for (int u = 0; u < 64; u++) {
        float g = sh_as[ln][u];
        int base = u * 128 + w;
#pragma unroll
        for (int a = 0; a < 4; a++) acc += g * fa[a] * w0[base + a * 32];
    }
    float os = acc * NORM256_F;
    float sn = C_S_F * sc_s[n * 32 + w] + C_X_F * os;
    snew[n * 32 + w] = sn;
    float sig = 1.0f / (1.0f + __expf(-sn));
    s[n * 32 + w] += sn * sig;   // silu(sn)
}

// ------------------------------------------- second fctp (64-wide) + v update
__global__ __launch_bounds__(256, 4) void node_update_v(
    const float* __restrict__ agg_v, const float* __restrict__ attr,
    const float* __restrict__ W1, const float* __restrict__ sc_v,
    const float* __restrict__ snew, float* __restrict__ v, int N) {
    __shared__ float w1[8192];
    __shared__ float sh_av[8][192];
    int ln = threadIdx.x >> 5, w = threadIdx.x & 31;
    int n = blockIdx.x * 8 + ln;
    bool valid = n < N;
    if (valid) {
#pragma unroll
        for (int i = 0; i < 6; i++)
            sh_av[ln][w * 6 + i] = agg_v[(size_t)n * 192 + w * 6 + i];
    }
    for (int i = threadIdx.x; i < 8192; i += 256) w1[i] = W1[i];
    __syncthreads();
    if (!valid) return;
    float4 at = *(const float4*)(attr + n * 4);
    float fa[4] = {at.x, at.y, at.z, at.w};
    float a0 = 0.f, a1 = 0.f, a2 = 0.f;
    for (int u = 0; u < 64; u++) {
        float g0 = sh_av[ln][u * 3 + 0];
        float g1 = sh_av[ln][u * 3 + 1];
        float g2 = sh_av[ln][u * 3 + 2];
        int base = u * 128 + w;
#pragma unroll
        for (int a = 0; a < 4; a++) {
            float f = fa[a];
            float W1v = w1[base + a * 32];
            a0 += g0 * f * W1v; a1 += g1 * f * W1v; a2 += g2 * f * W1v;
        }
    }
    float sn = snew[n * 32 + w];
    float sig = 1.0f / (1.0f + __expf(-sn));
    float ov0 = a0 * NORM256_F, ov1 = a1 * NORM256_F, ov2 = a2 * NORM256_F;
    v[n * 96 + w * 3 + 0] += (C_S_F * sc_v[n * 96 + w * 3 + 0] + C_X_F * ov0) * sig;
    v[n * 96 + w * 3 + 1] += (C_S_F * sc_v[n * 96 + w * 3 + 1] + C_X_F * ov1) * sig;
    v[n * 96 + w * 3 + 2] += (C_S_F * sc_v[n * 96 + w * 3 + 2] + C_X_F * ov2) * sig;
}

// ---------------------------------------------------------------- readout
__global__ __launch_bounds__(256) void readout(
    const float* __restrict__ s, const float* __restrict__ attr,
    const float* __restrict__ Wread, const int* __restrict__ batch,
    float* __restrict__ out, int N, float pool_scale) {
    __shared__ float wr[2048];
    for (int i = threadIdx.x; i < 2048; i += 256) wr[i] = Wread[i];
    int ln = threadIdx.x >> 4, w = threadIdx.x & 15;
    int n = blockIdx.x * 16 + ln;
    __syncthreads();
    if (n >= N) return;
    float4 at = *(const float4*)(attr + n * 4);
    float fa[4] = {at.x, at.y, at.z, at.w};
    float acc = 0.f;
    for (int u = 0; u < 32; u++) {
        float su = s[n * 32 + u];
        int base = u * 64 + w;
#pragma unroll
        for (int a = 0; a < 4; a++) acc += su * fa[a] * wr[base + a * 16];
    }
    atomicAdd(&out[batch[n] * 16 + w], acc * NORM128_F * pool_scale);
}

// ---------------------------------------------------------------- launch
extern "C" void kernel_launch(void* const* d_in, const int* in_sizes, int n_in,
                              void* d_out, int out_size, void* d_ws, size_t ws_size,
                              hipStream_t stream) {
    const float* x        = (const float*)d_in[0];
    const float* nattr    = (const float*)d_in[1];
    const float* edge_vec = (const float*)d_in[2];
    const int*   batch    = (const int*)d_in[3];
    const int*   esrc     = (const int*)d_in[4];
    const int*   edst     = (const int*)d_in[5];
    const float* Wsc0  = (const float*)d_in[6];
    const float* Wsc1  = (const float*)d_in[7];
    const float* Wl10  = (const float*)d_in[8];
    const float* Wl11  = (const float*)d_in[9];
    const float* Wfc1  = (const float*)d_in[10];
    const float* Wfc2  = (const float*)d_in[11];
    const float* Wl20  = (const float*)d_in[12];
    const float* Wl21  = (const float*)d_in[13];
    const float* Wread = (const float*)d_in[14];

    int N = in_sizes[0] / (MUL * 4);
    int E = in_sizes[2] / 3;

    float* p = (float*)d_ws;
    float* s_buf  = p; p += (size_t)N * 32;
    float* v_buf  = p; p += (size_t)N * 96;
    float* sc_s   = p; p += (size_t)N * 32;
    float* sc_v   = p; p += (size_t)N * 96;
    float* xs_buf = p; p += (size_t)N * 32;
    float* xv_buf = p; p += (size_t)N * 96;
    float* snew   = p; p += (size_t)N * 32;
    float* agg_s  = p; p += (size_t)N * 64;   // agg_s and agg_v contiguous:
    float* agg_v  = p; p += (size_t)N * 192;  // one memset covers both

    init_sv<<<(N * 128 + 255) / 256, 256, 0, stream>>>(x, s_buf, v_buf, N);
    hipMemsetAsync(d_out, 0, (size_t)out_size * sizeof(float), stream);

    for (int l = 0; l < 2; l++) {
        node_s_fctp<<<(N + 7) / 8, 256, 0, stream>>>(
            s_buf, nattr, Wsc0 + l * 4096, Wl10 + l * 4096, sc_s, xs_buf, N);
        node_v_fctp<<<(N + 7) / 8, 256, 0, stream>>>(
            v_buf, nattr, Wsc1 + l * 4096, Wl11 + l * 4096, sc_v, xv_buf, N);
        hipMemsetAsync(agg_s, 0, (size_t)N * 256 * sizeof(float), stream);
        edge_msg<<<(E + 63) / 64, 256, 0, stream>>>(
            edge_vec, esrc, edst, xs_buf, xv_buf,
            Wfc1 + l * 640, Wfc2 + l * 8192, agg_s, agg_v, E);
        node_update_s<<<(N + 7) / 8, 256, 0, stream>>>(
            agg_s, nattr, Wl20 + l * 8192, sc_s, s_buf, snew, N);
        node_update_v<<<(N + 7) / 8, 256, 0, stream>>>(
            agg_v, nattr, Wl21 + l * 8192, sc_v, snew, v_buf, N);
    }

    float pool_scale = (float)(1.0 / sqrt((double)N / (double)NGRAPH));
    readout<<<(N + 15) / 16, 256, 0, stream>>>(
        s_buf, nattr, Wread, batch, (float*)d_out, N, pool_scale);
}

// Round 2
// 747.133 us; speedup vs baseline: 2.3092x; 2.3092x over previous
//
#include <hip/hip_runtime.h>
#include <math.h>

#define MUL 32
#define NATTR 4
#define NBASIS 10
#define HID 64
#define OUT_DIM 16
#define NGRAPH 8

#define PI_F 3.14159265358979323846f
#define SQRT3_F 1.7320508075688772f
#define INV_SQRT3_F 0.5773502691896258f
#define INV_SQRT10_F 0.31622776601683794f
#define INV_SQRTNN_F 0.17677669529663687f   // 1/sqrt(32)
#define NORM128_F 0.08838834764831845f      // 1/sqrt(128)
#define NORM256_F 0.0625f                   // 1/sqrt(256)
#define C_S_F 0.3826834323650898f           // sin(pi/8)
#define C_X_F 0.9238795325112867f           // cos(pi/8)
#define CSTEP_F (4.0f/9.0f)                 // linspace(0,4,10) step

// ---------------------------------------------------------------- init s,v
__global__ void init_sv(const float* __restrict__ x,
                        float* __restrict__ s, float* __restrict__ v, int N) {
    int i = blockIdx.x * 256 + threadIdx.x;
    if (i >= N * 128) return;
    int n = i >> 7, c = i & 127;
    float val = x[i];
    if (c < 32) s[n * 32 + c] = val;
    else        v[n * 96 + (c - 32)] = val;
}

// ---------------------------------------------------------------- CSR build
__global__ void csr_count(const int* __restrict__ edst, int* __restrict__ cnt, int E) {
    int e = blockIdx.x * 256 + threadIdx.x;
    if (e < E) atomicAdd(&cnt[edst[e]], 1);
}

__global__ void csr_scan(const int* __restrict__ cnt, int* __restrict__ off,
                         int* __restrict__ cursor, int N) {
    __shared__ int sums[256];
    int t = threadIdx.x;
    int chunk = (N + 255) / 256;
    int lo = t * chunk, hi = lo + chunk; if (hi > N) hi = N;
    int s = 0;
    for (int i = lo; i < hi; i++) s += cnt[i];
    sums[t] = s;
    __syncthreads();
    for (int d = 1; d < 256; d <<= 1) {
        int v = (t >= d) ? sums[t - d] : 0;
        __syncthreads();
        sums[t] += v;
        __syncthreads();
    }
    int run = (t == 0) ? 0 : sums[t - 1];
    for (int i = lo; i < hi; i++) {
        off[i] = run; cursor[i] = run;
        run += cnt[i];
    }
}

__global__ void csr_fill(const int* __restrict__ edst, int* __restrict__ cursor,
                         int* __restrict__ eid, int E) {
    int e = blockIdx.x * 256 + threadIdx.x;
    if (e < E) { int p = atomicAdd(&cursor[edst[e]], 1); eid[p] = e; }
}

// ------------------------------------------- node fctp, scalar path (s -> 2 outputs)
__global__ __launch_bounds__(256, 4) void node_s_fctp(
    const float* __restrict__ s, const float* __restrict__ attr,
    const float* __restrict__ W0, const float* __restrict__ W1,
    float* __restrict__ out0, float* __restrict__ out1, int N) {
    __shared__ float w0[4096], w1[4096];
    __shared__ float sh_s[8][32];
    int ln = threadIdx.x >> 5, w = threadIdx.x & 31;
    int n = blockIdx.x * 8 + ln;
    bool valid = n < N;
    if (valid) sh_s[ln][w] = s[n * 32 + w];
    for (int i = threadIdx.x; i < 4096; i += 256) { w0[i] = W0[i]; w1[i] = W1[i]; }
    __syncthreads();
    if (!valid) return;
    float4 at = *(const float4*)(attr + n * 4);
    float fa[4] = {at.x, at.y, at.z, at.w};
    float acc0 = 0.f, acc1 = 0.f;
    for (int u = 0; u < 32; u++) {
        float su = sh_s[ln][u];
        int base = u * 128 + w;
#pragma unroll
        for (int a = 0; a < 4; a++) {
            float c = su * fa[a];
            acc0 += c * w0[base + a * 32];
            acc1 += c * w1[base + a * 32];
        }
    }
    out0[n * 32 + w] = acc0 * NORM128_F;
    out1[n * 32 + w] = acc1 * NORM128_F;
}

// ------------------------------------------- node fctp, vector path (v -> 2 outputs)
__global__ __launch_bounds__(256, 4) void node_v_fctp(
    const float* __restrict__ v, const float* __restrict__ attr,
    const float* __restrict__ W0, const float* __restrict__ W1,
    float* __restrict__ out0, float* __restrict__ out1, int N) {
    __shared__ float w0[4096], w1[4096];
    __shared__ float sh_v[8][96];
    int ln = threadIdx.x >> 5, w = threadIdx.x & 31;
    int n = blockIdx.x * 8 + ln;
    bool valid = n < N;
    if (valid) {
        sh_v[ln][w * 3 + 0] = v[n * 96 + w * 3 + 0];
        sh_v[ln][w * 3 + 1] = v[n * 96 + w * 3 + 1];
        sh_v[ln][w * 3 + 2] = v[n * 96 + w * 3 + 2];
    }
    for (int i = threadIdx.x; i < 4096; i += 256) { w0[i] = W0[i]; w1[i] = W1[i]; }
    __syncthreads();
    if (!valid) return;
    float4 at = *(const float4*)(attr + n * 4);
    float fa[4] = {at.x, at.y, at.z, at.w};
    float a00 = 0, a01 = 0, a02 = 0, a10 = 0, a11 = 0, a12 = 0;
    for (int u = 0; u < 32; u++) {
        float vu0 = sh_v[ln][u * 3 + 0];
        float vu1 = sh_v[ln][u * 3 + 1];
        float vu2 = sh_v[ln][u * 3 + 2];
        int base = u * 128 + w;
#pragma unroll
        for (int a = 0; a < 4; a++) {
            float f = fa[a];
            float c0 = vu0 * f, c1 = vu1 * f, c2 = vu2 * f;
            float W0v = w0[base + a * 32], W1v = w1[base + a * 32];
            a00 += c0 * W0v; a01 += c1 * W0v; a02 += c2 * W0v;
            a10 += c0 * W1v; a11 += c1 * W1v; a12 += c2 * W1v;
        }
    }
    out0[n * 96 + w * 3 + 0] = a00 * NORM128_F;
    out0[n * 96 + w * 3 + 1] = a01 * NORM128_F;
    out0[n * 96 + w * 3 + 2] = a02 * NORM128_F;
    out1[n * 96 + w * 3 + 0] = a10 * NORM128_F;
    out1[n * 96 + w * 3 + 1] = a11 * NORM128_F;
    out1[n * 96 + w * 3 + 2] = a12 * NORM128_F;
}

// ---------------------------------------------------------------- edge weights
// 64 edges per block: emb -> h (silu) -> w, write w[E][32][4] + y[E][4].
__global__ __launch_bounds__(256, 4) void edge_weights(
    const float* __restrict__ edge_vec,
    const float* __restrict__ Wfc1, const float* __restrict__ Wfc2,
    float* __restrict__ w_buf, float* __restrict__ y_buf, int E) {
    __shared__ float sh_wfc1[NBASIS * 64];   // [j][k]
    __shared__ float sh_embT[NBASIS * 64];   // [j][e]
    __shared__ float sh_h[64 * 65];          // [e][k], stride 65

    int tid = threadIdx.x;
    int e0 = blockIdx.x * 64;

    for (int i = tid; i < 640; i += 256) sh_wfc1[i] = Wfc1[i];
    if (tid < 64) {
        int e = e0 + tid;
        float ex = 0.f, ey = 0.f, ez = 0.f;
        if (e < E) {
            ex = edge_vec[e * 3 + 0]; ey = edge_vec[e * 3 + 1]; ez = edge_vec[e * 3 + 2];
        }
        float len = sqrtf(ex * ex + ey * ey + ez * ez);
        float rinv = SQRT3_F / (len + 1e-9f);
        if (e < E) {
            float4 y4 = {ex * rinv, ey * rinv, ez * rinv, len};
            *(float4*)(y_buf + (size_t)e * 4) = y4;
        }
        float uu = 2.0f * (len * 0.25f - 1.0f);
        float cut = (uu > 0.0f) ? 0.0f
                  : ((uu < -1.0f) ? 1.0f : 0.5f * (1.0f - __cosf(PI_F * uu)));
#pragma unroll
        for (int j = 0; j < NBASIS; j++) {
            float d = (len - j * CSTEP_F) * 2.5f;
            sh_embT[j * 64 + tid] = __expf(-d * d) * cut;
        }
    }
    __syncthreads();

    // ---- phase 1: h[e][k] = silu((emb @ Wfc1)/sqrt(10))
    {
        int k = tid & 63;
        int eb = (tid >> 6) * 16;
        float acc[16];
#pragma unroll
        for (int i = 0; i < 16; i++) acc[i] = 0.f;
#pragma unroll
        for (int j = 0; j < NBASIS; j++) {
            float wv = sh_wfc1[j * 64 + k];
#pragma unroll
            for (int i = 0; i < 16; i++) acc[i] += wv * sh_embT[j * 64 + eb + i];
        }
#pragma unroll
        for (int i = 0; i < 16; i++) {
            float a = acc[i] * INV_SQRT10_F;
            sh_h[(eb + i) * 65 + k] = a / (1.0f + __expf(-a));
        }
    }
    __syncthreads();

    // ---- phase 2: w[e][c] = (h @ Wfc2)/8 ; register tile 4 edges x 8 outputs
    // output channel wq = wt*8+j; store transposed: w_buf[e*128 + (wq&31)*4 + (wq>>5)]
    {
        int wt = tid & 15;   // outputs wt*8 .. wt*8+7
        int et = tid >> 4;   // edges  et*4 .. et*4+3
        float acc[4][8];
#pragma unroll
        for (int ie = 0; ie < 4; ie++)
#pragma unroll
            for (int j = 0; j < 8; j++) acc[ie][j] = 0.f;
        const float* W2 = Wfc2 + wt * 8;
#pragma unroll 4
        for (int k = 0; k < HID; k++) {
            float4 b0 = *(const float4*)(W2 + k * 128);
            float4 b1 = *(const float4*)(W2 + k * 128 + 4);
            float bv[8] = {b0.x, b0.y, b0.z, b0.w, b1.x, b1.y, b1.z, b1.w};
            float hv[4];
#pragma unroll
            for (int ie = 0; ie < 4; ie++) hv[ie] = sh_h[(et * 4 + ie) * 65 + k];
#pragma unroll
            for (int ie = 0; ie < 4; ie++)
#pragma unroll
                for (int j = 0; j < 8; j++) acc[ie][j] += hv[ie] * bv[j];
        }
        int c = wt >> 2;             // wq>>5
        int u0 = (wt & 3) * 8;       // wq&31 base
#pragma unroll
        for (int ie = 0; ie < 4; ie++) {
            int e = e0 + et * 4 + ie;
            if (e >= E) continue;
            float* dst = w_buf + (size_t)e * 128 + c;
#pragma unroll
            for (int j = 0; j < 8; j++) dst[(u0 + j) * 4] = acc[ie][j] * 0.125f;
        }
    }
}

// ---------------------------------------------------------------- gather
// one wave per dst node; half-wave per edge; lane u = channel u (0..31).
__global__ __launch_bounds__(256, 4) void gather_msgs(
    const int* __restrict__ off, const int* __restrict__ cnt,
    const int* __restrict__ eid, const int* __restrict__ esrc,
    const float* __restrict__ w_buf, const float* __restrict__ y_buf,
    const float* __restrict__ xs, const float* __restrict__ xv,
    float* __restrict__ agg_s, float* __restrict__ agg_v, int N) {
    int node = blockIdx.x * 4 + (threadIdx.x >> 6);
    if (node >= N) return;
    int lane = threadIdx.x & 63;
    int half = lane >> 5;
    int u = lane & 31;
    int o = off[node], deg = cnt[node];
    float as0 = 0, as1 = 0;
    float av00 = 0, av01 = 0, av02 = 0, av10 = 0, av11 = 0, av12 = 0;
    for (int i = half; i < deg; i += 2) {
        int e = eid[o + i];
        int src = esrc[e];
        float4 wv = *(const float4*)(w_buf + (size_t)e * 128 + u * 4);
        float4 y  = *(const float4*)(y_buf + (size_t)e * 4);
        float sE = xs[src * 32 + u];
        const float* vp = xv + src * 96 + u * 3;
        float v0 = vp[0], v1 = vp[1], v2 = vp[2];
        as0 += wv.x * sE;
        as1 += wv.y * (y.x * v0 + y.y * v1 + y.z * v2) * INV_SQRT3_F;
        float t = wv.z * sE;
        av00 += t * y.x;  av01 += t * y.y;  av02 += t * y.z;
        av10 += wv.w * v0; av11 += wv.w * v1; av12 += wv.w * v2;
    }
    as0 += __shfl_down(as0, 32);  as1 += __shfl_down(as1, 32);
    av00 += __shfl_down(av00, 32); av01 += __shfl_down(av01, 32); av02 += __shfl_down(av02, 32);
    av10 += __shfl_down(av10, 32); av11 += __shfl_down(av11, 32); av12 += __shfl_down(av12, 32);
    if (half == 0) {
        agg_s[node * 64 + u]      = as0 * INV_SQRTNN_F;
        agg_s[node * 64 + 32 + u] = as1 * INV_SQRTNN_F;
        float* av = agg_v + (size_t)node * 192;
        av[u * 3 + 0]      = av00 * INV_SQRTNN_F;
        av[u * 3 + 1]      = av01 * INV_SQRTNN_F;
        av[u * 3 + 2]      = av02 * INV_SQRTNN_F;
        av[96 + u * 3 + 0] = av10 * INV_SQRTNN_F;
        av[96 + u * 3 + 1] = av11 * INV_SQRTNN_F;
        av[96 + u * 3 + 2] = av12 * INV_SQRTNN_F;
    }
}

// ------------------------------------------- second fctp (64-wide) + s update
__global__ __launch_bounds__(256, 4) void node_update_s(
    const float* __restrict__ agg_s, const float* __restrict__ attr,
    const float* __restrict__ W0, const float* __restrict__ sc_s,
    float* __restrict__ s, float* __restrict__ snew, int N) {
    __shared__ float w0[8192];
    __shared__ float sh_as[8][64];
    int ln = threadIdx.x >> 5, w = threadIdx.x & 31;
    int n = blockIdx.x * 8 + ln;
    bool valid = n < N;
    if (valid) {
        sh_as[ln][w] = agg_s[n * 64 + w];
        sh_as[ln][32 + w] = agg_s[n * 64 + 32 + w];
    }
    for (int i = threadIdx.x; i < 8192; i += 256) w0[i] = W0[i];
    __syncthreads();
    if (!valid) return;
    float4 at = *(const float4*)(attr + n * 4);
    float fa[4] = {at.x, at.y, at.z, at.w};
    float acc = 0.f;
    for (int u = 0; u < 64; u++) {
        float g = sh_as[ln][u];
        int base = u * 128 + w;
#pragma unroll
        for (int a = 0; a < 4; a++) acc += g * fa[a] * w0[base + a * 32];
    }
    float os = acc * NORM256_F;
    float sn = C_S_F * sc_s[n * 32 + w] + C_X_F * os;
    snew[n * 32 + w] = sn;
    float sig = 1.0f / (1.0f + __expf(-sn));
    s[n * 32 + w] += sn * sig;   // silu(sn)
}

// ------------------------------------------- second fctp (64-wide) + v update
__global__ __launch_bounds__(256, 4) void node_update_v(
    const float* __restrict__ agg_v, const float* __restrict__ attr,
    const float* __restrict__ W1, const float* __restrict__ sc_v,
    const float* __restrict__ snew, float* __restrict__ v, int N) {
    __shared__ float w1[8192];
    __shared__ float sh_av[8][192];
    int ln = threadIdx.x >> 5, w = threadIdx.x & 31;
    int n = blockIdx.x * 8 + ln;
    bool valid = n < N;
    if (valid) {
#pragma unroll
        for (int i = 0; i < 6; i++)
            sh_av[ln][w * 6 + i] = agg_v[(size_t)n * 192 + w * 6 + i];
    }
    for (int i = threadIdx.x; i < 8192; i += 256) w1[i] = W1[i];
    __syncthreads();
    if (!valid) return;
    float4 at = *(const float4*)(attr + n * 4);
    float fa[4] = {at.x, at.y, at.z, at.w};
    float a0 = 0.f, a1 = 0.f, a2 = 0.f;
    for (int u = 0; u < 64; u++) {
        float g0 = sh_av[ln][u * 3 + 0];
        float g1 = sh_av[ln][u * 3 + 1];
        float g2 = sh_av[ln][u * 3 + 2];
        int base = u * 128 + w;
#pragma unroll
        for (int a = 0; a < 4; a++) {
            float f = fa[a];
            float W1v = w1[base + a * 32];
            a0 += g0 * f * W1v; a1 += g1 * f * W1v; a2 += g2 * f * W1v;
        }
    }
    float sn = snew[n * 32 + w];
    float sig = 1.0f / (1.0f + __expf(-sn));
    float ov0 = a0 * NORM256_F, ov1 = a1 * NORM256_F, ov2 = a2 * NORM256_F;
    v[n * 96 + w * 3 + 0] += (C_S_F * sc_v[n * 96 + w * 3 + 0] + C_X_F * ov0) * sig;
    v[n * 96 + w * 3 + 1] += (C_S_F * sc_v[n * 96 + w * 3 + 1] + C_X_F * ov1) * sig;
    v[n * 96 + w * 3 + 2] += (C_S_F * sc_v[n * 96 + w * 3 + 2] + C_X_F * ov2) * sig;
}

// ---------------------------------------------------------------- readout
__global__ __launch_bounds__(256) void readout(
    const float* __restrict__ s, const float* __restrict__ attr,
    const float* __restrict__ Wread, const int* __restrict__ batch,
    float* __restrict__ out, int N, float pool_scale) {
    __shared__ float wr[2048];
    for (int i = threadIdx.x; i < 2048; i += 256) wr[i] = Wread[i];
    int ln = threadIdx.x >> 4, w = threadIdx.x & 15;
    int n = blockIdx.x * 16 + ln;
    __syncthreads();
    if (n >= N) return;
    float4 at = *(const float4*)(attr + n * 4);
    float fa[4] = {at.x, at.y, at.z, at.w};
    float acc = 0.f;
    for (int u = 0; u < 32; u++) {
        float su = s[n * 32 + u];
        int base = u * 64 + w;
#pragma unroll
        for (int a = 0; a < 4; a++) acc += su * fa[a] * wr[base + a * 16];
    }
    atomicAdd(&out[batch[n] * 16 + w], acc * NORM128_F * pool_scale);
}

// ---------------------------------------------------------------- launch
extern "C" void kernel_launch(void* const* d_in, const int* in_sizes, int n_in,
                              void* d_out, int out_size, void* d_ws, size_t ws_size,
                              hipStream_t stream) {
    const float* x        = (const float*)d_in[0];
    const float* nattr    = (const float*)d_in[1];
    const float* edge_vec = (const float*)d_in[2];
    const int*   batch    = (const int*)d_in[3];
    const int*   esrc     = (const int*)d_in[4];
    const int*   edst     = (const int*)d_in[5];
    const float* Wsc0  = (const float*)d_in[6];
    const float* Wsc1  = (const float*)d_in[7];
    const float* Wl10  = (const float*)d_in[8];
    const float* Wl11  = (const float*)d_in[9];
    const float* Wfc1  = (const float*)d_in[10];
    const float* Wfc2  = (const float*)d_in[11];
    const float* Wl20  = (const float*)d_in[12];
    const float* Wl21  = (const float*)d_in[13];
    const float* Wread = (const float*)d_in[14];

    int N = in_sizes[0] / (MUL * 4);
    int E = in_sizes[2] / 3;

    float* p = (float*)d_ws;
    float* w_buf  = p; p += (size_t)E * 128;   // 16B-aligned float4 layout [e][u][c]
    float* y_buf  = p; p += (size_t)E * 4;
    float* s_buf  = p; p += (size_t)N * 32;
    float* v_buf  = p; p += (size_t)N * 96;
    float* sc_s   = p; p += (size_t)N * 32;
    float* sc_v   = p; p += (size_t)N * 96;
    float* xs_buf = p; p += (size_t)N * 32;
    float* xv_buf = p; p += (size_t)N * 96;
    float* snew   = p; p += (size_t)N * 32;
    float* agg_s  = p; p += (size_t)N * 64;
    float* agg_v  = p; p += (size_t)N * 192;
    int* cnt    = (int*)p; p += N;
    int* off    = (int*)p; p += N;
    int* cursor = (int*)p; p += N;
    int* eid    = (int*)p; p += E;

    init_sv<<<(N * 128 + 255) / 256, 256, 0, stream>>>(x, s_buf, v_buf, N);
    hipMemsetAsync(d_out, 0, (size_t)out_size * sizeof(float), stream);

    // CSR by destination
    hipMemsetAsync(cnt, 0, (size_t)N * sizeof(int), stream);
    csr_count<<<(E + 255) / 256, 256, 0, stream>>>(edst, cnt, E);
    csr_scan<<<1, 256, 0, stream>>>(cnt, off, cursor, N);
    csr_fill<<<(E + 255) / 256, 256, 0, stream>>>(edst, cursor, eid, E);

    for (int l = 0; l < 2; l++) {
        node_s_fctp<<<(N + 7) / 8, 256, 0, stream>>>(
            s_buf, nattr, Wsc0 + l * 4096, Wl10 + l * 4096, sc_s, xs_buf, N);
        node_v_fctp<<<(N + 7) / 8, 256, 0, stream>>>(
            v_buf, nattr, Wsc1 + l * 4096, Wl11 + l * 4096, sc_v, xv_buf, N);
        edge_weights<<<(E + 63) / 64, 256, 0, stream>>>(
            edge_vec, Wfc1 + l * 640, Wfc2 + l * 8192, w_buf, y_buf, E);
        gather_msgs<<<(N + 3) / 4, 256, 0, stream>>>(
            off, cnt, eid, esrc, w_buf, y_buf, xs_buf, xv_buf, agg_s, agg_v, N);
        node_update_s<<<(N + 7) / 8, 256, 0, stream>>>(
            agg_s, nattr, Wl20 + l * 8192, sc_s, s_buf, snew, N);
        node_update_v<<<(N + 7) / 8, 256, 0, stream>>>(
            agg_v, nattr, Wl21 + l * 8192, sc_v, snew, v_buf, N);
    }

    float pool_scale = (float)(1.0 / sqrt((double)N / (double)NGRAPH));
    readout<<<(N + 15) / 16, 256, 0, stream>>>(
        s_buf, nattr, Wread, batch, (float*)d_out, N, pool_scale);
}